// Round 1
// baseline (1033.303 us; speedup 1.0000x reference)
//
#include <hip/hip_runtime.h>
#include <math.h>

#define NN 30000
#define NE 480000
#define TPB 256
#define ETPB 64

// ---- CSR-path workspace layout (float offsets) ----
// cnt, c2, Z, base are contiguous: zeroed by ONE memset
#define NG_OFF    0           // 600000 g vectors (Wd folded)
#define NW1K_OFF  600000      // 512
#define NW1V_OFF  600512      // 512
#define NW2K_OFF  601024      // 9216
#define NW2V_OFF  610240      // 9216
#define NCNT_OFF  619456      // 30000 int
#define NC2_OFF   649456      // 30000 int
#define NZ_OFF    679456      // 30000 f32
#define NBASE_OFF 709456      // 8 int
#define NOFF_OFF  709464      // 30000 int
#define NEVS_OFF  739464      // 480000 f32
#define NVSC_OFF  1219464     // 9600000 halfs
#define NTOT      6019464     // floats (~24.1 MB)

#define INV_SQRT8  0.35355339059327376f
#define SIG_SS     0.02209708691207961f
#define SIG_UU     0.01804219591217582f
#define SIG_SU     0.02209708691207961f
#define SIG_US     0.03125f
#define D0S        0.08838834764831845f
#define D1S        0.10206207261596575f

// single-wave block: HW executes a wave's DS ops in order; this only pins
// compile-time ordering (no s_barrier, no waitcnt drain). r13-verified.
#define WBAR() __builtin_amdgcn_wave_barrier()

typedef _Float16 half2v __attribute__((ext_vector_type(2)));
typedef _Float16 f16x4  __attribute__((ext_vector_type(4)));
typedef _Float16 f16x8  __attribute__((ext_vector_type(8)));
typedef float    f32x4  __attribute__((ext_vector_type(4)));

__device__ __forceinline__ float fdot2(half2v a, half2v b, float c) {
    return __builtin_amdgcn_fdot2(a, b, c, false);
}

// ---------- fused prep: weight pack (0..17) + g vectors (18..135) + edge hist (136..)
__global__ __launch_bounds__(TPB) void prep_all(
    const float* __restrict__ x, const int* __restrict__ ei,
    const float* __restrict__ wq0, const float* __restrict__ wq1,
    const float* __restrict__ wk1, const float* __restrict__ wk2,
    const float* __restrict__ wv1, const float* __restrict__ wv2,
    const float* __restrict__ wd0, const float* __restrict__ wd1,
    half2v* __restrict__ w1pk, half2v* __restrict__ w1pv,
    _Float16* __restrict__ w2fk, _Float16* __restrict__ w2fv,
    float* __restrict__ g, int* __restrict__ cnt)
{
    const int b = blockIdx.x;
    if (b < 18) {
        int tid = b * TPB + threadIdx.x;   // 4608 exactly
        {
            int p = tid / 2304, rem = tid % 2304;
            int fg = rem >> 6, l = rem & 63;
            int t = fg >> 1, s = fg & 1;
            int kbase = s * 32 + (l >> 4) * 8;
            int m = t * 16 + (l & 15);
            float sig = (m < 128) ? SIG_SS : (m < 192) ? SIG_UU
                      : (m < 256) ? SIG_SU : SIG_US;
            const float* W2 = p ? wv2 : wk2;
            _Float16* dst = (p ? w2fv : w2fk) + (size_t)(fg * 64 + l) * 8;
#pragma unroll
            for (int jj = 0; jj < 8; ++jj)
                dst[jj] = (_Float16)(W2[(size_t)(kbase + jj) * 288 + m] * sig);
        }
        if (tid < 512) {
            int hh = tid >> 3, a2 = tid & 7;
            w1pk[tid] = half2v{(_Float16)(wk1[(2 * a2) * 64 + hh] * 0.25f),
                               (_Float16)(wk1[(2 * a2 + 1) * 64 + hh] * 0.25f)};
            w1pv[tid] = half2v{(_Float16)(wv1[(2 * a2) * 64 + hh] * 0.25f),
                               (_Float16)(wv1[(2 * a2 + 1) * 64 + hh] * 0.25f)};
        }
    } else if (b < 136) {
        // ---- per-node g = Wd-folded q (r12-verified) ----
        int n = (b - 18) * TPB + threadIdx.x;
        if (n >= NN) return;
        const float* xr = x + (size_t)n * 40;
        float* o = g + (size_t)n * 20;
        float q0[8];
#pragma unroll
        for (int bb = 0; bb < 8; ++bb) {
            float acc = 0.f;
#pragma unroll
            for (int a = 0; a < 16; ++a) acc += xr[a] * wq0[a * 8 + bb];
            q0[bb] = acc * 0.25f;
        }
#pragma unroll
        for (int bb = 0; bb < 8; ++bb) {
            float acc = 0.f;
#pragma unroll
            for (int a = 0; a < 8; ++a) acc += q0[a] * wd0[a * 8 + bb];
            o[bb] = acc * D0S;
        }
        float q1[4][3];
#pragma unroll
        for (int bb = 0; bb < 4; ++bb)
#pragma unroll
            for (int c = 0; c < 3; ++c) {
                float acc = 0.f;
#pragma unroll
                for (int a = 0; a < 8; ++a) acc += xr[16 + a * 3 + c] * wq1[a * 4 + bb];
                q1[bb][c] = acc * INV_SQRT8;
            }
#pragma unroll
        for (int bb = 0; bb < 4; ++bb)
#pragma unroll
            for (int c = 0; c < 3; ++c) {
                float acc = 0.f;
#pragma unroll
                for (int a = 0; a < 4; ++a) acc += q1[a][c] * wd1[a * 4 + bb];
                o[8 + bb * 3 + c] = acc * D1S;
            }
    } else {
        // ---- edge histogram (cnt pre-zeroed by memset) ----
        int e = (b - 136) * TPB + threadIdx.x;   // 1875 blocks, exact
        atomicAdd(cnt + ei[NE + e], 1);
    }
}

// ---------- parallel order-free scan: block-local prefix + atomic base ----------
// Bases non-monotonic across blocks; CSR only needs disjoint contiguous segments
// (node_gather reads cnt[j] for lengths, never offs[j+1]-offs[j]).
__global__ __launch_bounds__(TPB) void scan_blk(const int* __restrict__ cnt,
                                                int* __restrict__ offs,
                                                int* __restrict__ base)
{
    __shared__ int sdata[TPB];
    __shared__ int bbase;
    const int t = threadIdx.x;
    const int idx = blockIdx.x * TPB + t;
    const int v = (idx < NN) ? cnt[idx] : 0;
    sdata[t] = v;
    __syncthreads();
    for (int off = 1; off < TPB; off <<= 1) {
        int u = (t >= off) ? sdata[t - off] : 0;
        __syncthreads();
        sdata[t] += u;
        __syncthreads();
    }
    if (t == TPB - 1) bbase = atomicAdd(base, sdata[TPB - 1]);
    __syncthreads();
    if (idx < NN) offs[idx] = bbase + sdata[t] - v;   // exclusive within block
}

// ---------- fused k+v edge kernel ----------
// r16: LDS diet for occupancy. h-compute re-assigned so each thread computes
// exactly its OWN MFMA B-fragment k-range ({8q..8q+7} u {32+8q..+7}) -> B
// fragments live in registers, sh_hv + h-staging deleted. sh_d -> shfl_xor
// reduce; sh_pe -> shfl broadcast. x row loaded ONCE (kept in regs across
// both epilogues); g[j] prefetched before K GEMM. LDS 12288 -> 9344 B:
// blocks/CU 13 -> 16 (VGPR cap 128 via launch_bounds = 4 waves/SIMD = 16/CU).
__global__ __launch_bounds__(ETPB, 4) void edge_fused(
    const float* __restrict__ x, const int* __restrict__ ei,
    const float* __restrict__ eattr, const float* __restrict__ emb,
    const float* __restrict__ el,
    const half2v* __restrict__ w1pk, const f16x8* __restrict__ w2fk,
    const half2v* __restrict__ w1pv, const f16x8* __restrict__ w2fv,
    const float* __restrict__ gn, const int* __restrict__ offs,
    int* __restrict__ c2, float* __restrict__ Z,
    float* __restrict__ evs, _Float16* __restrict__ vsc)
{
    __shared__ __align__(16) _Float16 sh_R[16][292];  // R dumps only

    const int l = threadIdx.x;            // single wave
    const int q = l >> 4, n = l & 15;
    const int e = blockIdx.x * 16 + n;
    const int i = ei[e];
    const int j = ei[NE + e];
    const float4 ea = *(const float4*)(eattr + (size_t)e * 4);
    const float y0 = ea.x, y1x = ea.y, y1y = ea.z, y1z = ea.w;
    const int b0 = (q < 2) ? (4 * q) : (2 * (q - 2));
    const float len = el[e];

    // in-kernel rank (CSR slot); issued first so atomic latency hides under h
    int pe0 = 0;
    if (l < 16) pe0 = offs[j] + atomicAdd(c2 + j, 1);

    // ---- both hidden layers; B fragments register-resident ----
    // thread (q,n) computes k in {8q..8q+7} (B0) and {32+8q..32+8q+7} (B1),
    // which is exactly the 16x16x32 MFMA B-lane-layout for lane l = 16q+n.
    f16x8 Bk0, Bk1, Bv0, Bv1;
    {
        half2v em2[8];
        const float4* ep = (const float4*)(emb + (size_t)e * 16);
#pragma unroll
        for (int p = 0; p < 4; ++p) {
            float4 v = ep[p];
            em2[2 * p]     = half2v{(_Float16)v.x, (_Float16)v.y};
            em2[2 * p + 1] = half2v{(_Float16)v.z, (_Float16)v.w};
        }
#pragma unroll
        for (int hf = 0; hf < 2; ++hf) {
            f16x8 hk, hv;
#pragma unroll
            for (int ii = 0; ii < 8; ++ii) {
                const int k = hf * 32 + q * 8 + ii;
                const half2v* wrk = w1pk + (size_t)k * 8;
                const half2v* wrv = w1pv + (size_t)k * 8;
                float a0 = 0.f, a1 = 0.f, c0 = 0.f, c1 = 0.f;
#pragma unroll
                for (int a2 = 0; a2 < 4; ++a2) {
                    a0 = fdot2(em2[2 * a2],     wrk[2 * a2],     a0);
                    a1 = fdot2(em2[2 * a2 + 1], wrk[2 * a2 + 1], a1);
                    c0 = fdot2(em2[2 * a2],     wrv[2 * a2],     c0);
                    c1 = fdot2(em2[2 * a2 + 1], wrv[2 * a2 + 1], c1);
                }
                const float zk = a0 + a1, zv = c0 + c1;
                hk[ii] = (_Float16)(zk * __builtin_amdgcn_rcpf(1.f + __expf(-zk)));
                hv[ii] = (_Float16)(zv * __builtin_amdgcn_rcpf(1.f + __expf(-zv)));
            }
            if (hf == 0) { Bk0 = hk; Bv0 = hv; } else { Bk1 = hk; Bv1 = hv; }
        }
    }

    // ---- prefetch g[j] slice needed by this thread's k-epilogue b-slice ----
    float gjv[6];
    {
        const float* gj = gn + (size_t)j * 20;
        if (q < 2) {
            float4 t4 = *(const float4*)(gj + b0);
            gjv[0] = t4.x; gjv[1] = t4.y; gjv[2] = t4.z; gjv[3] = t4.w;
            gjv[4] = 0.f;  gjv[5] = 0.f;
        } else {
            const float* gr = gj + 8 + b0 * 3;
#pragma unroll
            for (int r = 0; r < 6; ++r) gjv[r] = gr[r];
        }
    }

    // ================= K GEMM (B from registers) =================
    {
        f32x4 acc[18];
#pragma unroll
        for (int t = 0; t < 18; ++t) acc[t] = f32x4{0.f, 0.f, 0.f, 0.f};
#pragma unroll
        for (int t = 0; t < 18; ++t) {
            f16x8 A0 = w2fk[(t * 2 + 0) * 64 + l];
            f16x8 A1 = w2fk[(t * 2 + 1) * 64 + l];
            acc[t] = __builtin_amdgcn_mfma_f32_16x16x32_f16(A0, Bk0, acc[t], 0, 0, 0);
            acc[t] = __builtin_amdgcn_mfma_f32_16x16x32_f16(A1, Bk1, acc[t], 0, 0, 0);
        }
#pragma unroll
        for (int t = 0; t < 18; ++t) {
            f16x4 rv = {(_Float16)acc[t][0], (_Float16)acc[t][1],
                        (_Float16)acc[t][2], (_Float16)acc[t][3]};
            *(f16x4*)&sh_R[n][t * 16 + 4 * q] = rv;
        }
    }

    // ---- x row loaded ONCE, kept in regs across both epilogues ----
    float xr[40];
    {
        const float4* xp = (const float4*)(x + (size_t)i * 40);
#pragma unroll
        for (int p = 0; p < 10; ++p) {
            float4 v = xp[p];
            xr[4 * p] = v.x; xr[4 * p + 1] = v.y;
            xr[4 * p + 2] = v.z; xr[4 * p + 3] = v.w;
        }
    }
    WBAR();

    // ---- k epilogue: score partials (b-sliced; Wd pre-folded into g) ----
    float pd = 0.f;
    if (q < 2) {
        float ssv[4] = {0.f, 0.f, 0.f, 0.f};
        float uuv[4] = {0.f, 0.f, 0.f, 0.f};
#pragma unroll
        for (int a = 0; a < 16; ++a) {
            const f16x4 rv = *(const f16x4*)&sh_R[n][a * 8 + b0];
#pragma unroll
            for (int r = 0; r < 4; ++r) ssv[r] += xr[a] * (float)rv[r];
        }
#pragma unroll
        for (int a = 0; a < 8; ++a) {
            const float xy = xr[16 + a * 3] * y1x + xr[17 + a * 3] * y1y
                           + xr[18 + a * 3] * y1z;
            const f16x4 rv = *(const f16x4*)&sh_R[n][128 + a * 8 + b0];
#pragma unroll
            for (int r = 0; r < 4; ++r) uuv[r] += xy * (float)rv[r];
        }
#pragma unroll
        for (int r = 0; r < 4; ++r)
            pd += (y0 * ssv[r] + uuv[r]) * gjv[r];
    } else {
        float suv[2] = {0.f, 0.f};
        float usv[2][3] = {{0.f, 0.f, 0.f}, {0.f, 0.f, 0.f}};
#pragma unroll
        for (int a = 0; a < 16; ++a) {
            const half2v rv = *(const half2v*)&sh_R[n][192 + a * 4 + b0];
            suv[0] += xr[a] * (float)rv[0];
            suv[1] += xr[a] * (float)rv[1];
        }
#pragma unroll
        for (int a = 0; a < 8; ++a) {
            const half2v rv = *(const half2v*)&sh_R[n][256 + a * 4 + b0];
#pragma unroll
            for (int bb = 0; bb < 2; ++bb) {
                const float wv = (float)rv[bb];
                usv[bb][0] += xr[16 + a * 3] * wv;
                usv[bb][1] += xr[17 + a * 3] * wv;
                usv[bb][2] += xr[18 + a * 3] * wv;
            }
        }
#pragma unroll
        for (int bb = 0; bb < 2; ++bb) {
            const float k1x = suv[bb] * y1x + y0 * usv[bb][0];
            const float k1y = suv[bb] * y1y + y0 * usv[bb][1];
            const float k1z = suv[bb] * y1z + y0 * usv[bb][2];
            pd += k1x * gjv[bb * 3] + k1y * gjv[bb * 3 + 1] + k1z * gjv[bb * 3 + 2];
        }
    }
    // cross-q reduce (lanes 16q+n): no LDS
    pd += __shfl_xor(pd, 16);
    pd += __shfl_xor(pd, 32);
    const int pe = __shfl(pe0, n);   // broadcast CSR slot from lane n
    if (l < 16) {
        const float tt = 10.f * (1.f - len / 3.15f);
        float cut = 0.f;
        if (tt > 0.f) cut = __expf(-1.f / fmaxf(tt, 1e-6f));
        const float ev = cut * __expf(pd);
        evs[pe] = ev;
        atomicAdd(Z + j, ev);
    }
    WBAR();   // all k-epilogue sh_R reads precede v dump (in-order DS, pinned order)

    // ================= V GEMM (B from registers) =================
    {
        f32x4 acc[18];
#pragma unroll
        for (int t = 0; t < 18; ++t) acc[t] = f32x4{0.f, 0.f, 0.f, 0.f};
#pragma unroll
        for (int t = 0; t < 18; ++t) {
            f16x8 A0 = w2fv[(t * 2 + 0) * 64 + l];
            f16x8 A1 = w2fv[(t * 2 + 1) * 64 + l];
            acc[t] = __builtin_amdgcn_mfma_f32_16x16x32_f16(A0, Bv0, acc[t], 0, 0, 0);
            acc[t] = __builtin_amdgcn_mfma_f32_16x16x32_f16(A1, Bv1, acc[t], 0, 0, 0);
        }
#pragma unroll
        for (int t = 0; t < 18; ++t) {
            f16x4 rv = {(_Float16)acc[t][0], (_Float16)acc[t][1],
                        (_Float16)acc[t][2], (_Float16)acc[t][3]};
            *(f16x4*)&sh_R[n][t * 16 + 4 * q] = rv;
        }
    }
    WBAR();

    // ---- v epilogue: store 20-half record at CSR slot (xr reused) ----
    {
        _Float16* rec = vsc + (size_t)pe * 20;
        if (q < 2) {
            float ssv[4] = {0.f, 0.f, 0.f, 0.f};
            float uuv[4] = {0.f, 0.f, 0.f, 0.f};
#pragma unroll
            for (int a = 0; a < 16; ++a) {
                const f16x4 rv = *(const f16x4*)&sh_R[n][a * 8 + b0];
#pragma unroll
                for (int r = 0; r < 4; ++r) ssv[r] += xr[a] * (float)rv[r];
            }
#pragma unroll
            for (int a = 0; a < 8; ++a) {
                const float xy = xr[16 + a * 3] * y1x + xr[17 + a * 3] * y1y
                               + xr[18 + a * 3] * y1z;
                const f16x4 rv = *(const f16x4*)&sh_R[n][128 + a * 8 + b0];
#pragma unroll
                for (int r = 0; r < 4; ++r) uuv[r] += xy * (float)rv[r];
            }
            f16x4 o;
#pragma unroll
            for (int r = 0; r < 4; ++r) o[r] = (_Float16)(y0 * ssv[r] + uuv[r]);
            *(f16x4*)&rec[b0] = o;
        } else {
            float suv[2] = {0.f, 0.f};
            float usv[2][3] = {{0.f, 0.f, 0.f}, {0.f, 0.f, 0.f}};
#pragma unroll
            for (int a = 0; a < 16; ++a) {
                const half2v rv = *(const half2v*)&sh_R[n][192 + a * 4 + b0];
                suv[0] += xr[a] * (float)rv[0];
                suv[1] += xr[a] * (float)rv[1];
            }
#pragma unroll
            for (int a = 0; a < 8; ++a) {
                const half2v rv = *(const half2v*)&sh_R[n][256 + a * 4 + b0];
#pragma unroll
                for (int bb = 0; bb < 2; ++bb) {
                    const float wv = (float)rv[bb];
                    usv[bb][0] += xr[16 + a * 3] * wv;
                    usv[bb][1] += xr[17 + a * 3] * wv;
                    usv[bb][2] += xr[18 + a * 3] * wv;
                }
            }
            float k1v[2][3];
#pragma unroll
            for (int bb = 0; bb < 2; ++bb) {
                k1v[bb][0] = suv[bb] * y1x + y0 * usv[bb][0];
                k1v[bb][1] = suv[bb] * y1y + y0 * usv[bb][1];
                k1v[bb][2] = suv[bb] * y1z + y0 * usv[bb][2];
            }
            const int base = 8 + b0 * 3;
            *(half2v*)&rec[base]     = half2v{(_Float16)k1v[0][0], (_Float16)k1v[0][1]};
            *(half2v*)&rec[base + 2] = half2v{(_Float16)k1v[0][2], (_Float16)k1v[1][0]};
            *(half2v*)&rec[base + 4] = half2v{(_Float16)k1v[1][1], (_Float16)k1v[1][2]};
        }
    }
}

// ---------- node gather: Z precomputed; single weighted pass, zero atomics ----------
__global__ __launch_bounds__(TPB) void node_gather(
    const int* __restrict__ offs, const int* __restrict__ cntp,
    const float* __restrict__ Z,
    const float* __restrict__ evs, const _Float16* __restrict__ vsc,
    float* __restrict__ out)
{
    const int wv = threadIdx.x >> 6, lane = threadIdx.x & 63;
    const int j = blockIdx.x * 4 + wv;
    if (j >= NN) return;
    const int o0 = offs[j], cnt = cntp[j];
    const float zz = Z[j];
    const float invZ = (zz > 0.f) ? (1.f / zz) : 0.f;

    const int g = lane / 20, c = lane % 20;
    float acc = 0.f;
    if (g < 3) {
        for (int t = g; t < cnt; t += 3) {
            const float ev = evs[o0 + t];
            const float wgt = sqrtf(fmaxf(ev * invZ, 0.f));
            acc += wgt * (float)vsc[(size_t)(o0 + t) * 20 + c];
        }
    }
    const float a1 = __shfl(acc, lane + 20);
    const float a2 = __shfl(acc, lane + 40);
    if (lane < 20) out[(size_t)j * 20 + lane] = acc + a1 + a2;
}

extern "C" void kernel_launch(void* const* d_in, const int* in_sizes, int n_in,
                              void* d_out, int out_size, void* d_ws, size_t ws_size,
                              hipStream_t stream)
{
    const float* x     = (const float*)d_in[0];
    const int*   eidx  = (const int*)d_in[1];
    const float* eattr = (const float*)d_in[2];
    const float* emb   = (const float*)d_in[3];
    const float* elen  = (const float*)d_in[4];
    const float* wq0   = (const float*)d_in[5];
    const float* wq1   = (const float*)d_in[6];
    const float* wk1   = (const float*)d_in[7];
    const float* wk2   = (const float*)d_in[8];
    const float* wv1   = (const float*)d_in[9];
    const float* wv2   = (const float*)d_in[10];
    const float* wd0   = (const float*)d_in[11];
    const float* wd1   = (const float*)d_in[12];

    float* ws  = (float*)d_ws;
    float* out = (float*)d_out;

    half2v* w1pk = (half2v*)(ws + NW1K_OFF);
    half2v* w1pv = (half2v*)(ws + NW1V_OFF);
    _Float16* w2fk = (_Float16*)(ws + NW2K_OFF);
    _Float16* w2fv = (_Float16*)(ws + NW2V_OFF);
    int* cnt  = (int*)(ws + NCNT_OFF);
    int* c2   = (int*)(ws + NC2_OFF);
    float* Z  = ws + NZ_OFF;
    int* base = (int*)(ws + NBASE_OFF);
    int* offs = (int*)(ws + NOFF_OFF);
    float* evs = ws + NEVS_OFF;
    _Float16* vsc = (_Float16*)(ws + NVSC_OFF);

    // zero cnt + c2 + Z + base (contiguous) in one memset
    hipMemsetAsync(cnt, 0, (3 * NN + 8) * sizeof(int), stream);

    // prep: weights + g + histogram (1875 hist blocks)
    prep_all<<<136 + NE / TPB, TPB, 0, stream>>>(
        x, eidx, wq0, wq1, wk1, wk2, wv1, wv2, wd0, wd1,
        w1pk, w1pv, w2fk, w2fv, ws + NG_OFF, cnt);

    scan_blk<<<(NN + TPB - 1) / TPB, TPB, 0, stream>>>(cnt, offs, base);

    edge_fused<<<NE / 16, ETPB, 0, stream>>>(
        x, eidx, eattr, emb, elen,
        w1pk, (const f16x8*)w2fk, w1pv, (const f16x8*)w2fv,
        ws + NG_OFF, offs, c2, Z, evs, vsc);

    node_gather<<<(NN + 3) / 4, TPB, 0, stream>>>(offs, cnt, Z, evs, vsc, out);
}

// Round 2
// 781.351 us; speedup vs baseline: 1.3225x; 1.3225x over previous
//
#include <hip/hip_runtime.h>
#include <math.h>

#define NN 30000
#define NE 480000
#define TPB 256
#define ETPB 64

// ---- CSR-path workspace layout (float offsets) ----
// cnt, c2, Z, base are contiguous: zeroed by ONE memset
#define NG_OFF    0           // 600000 g vectors (Wd folded)
#define NW1K_OFF  600000      // 512
#define NW1V_OFF  600512      // 512
#define NW2K_OFF  601024      // 9216
#define NW2V_OFF  610240      // 9216
#define NCNT_OFF  619456      // 30000 int
#define NC2_OFF   649456      // 30000 int
#define NZ_OFF    679456      // 30000 f32
#define NBASE_OFF 709456      // 8 int
#define NOFF_OFF  709464      // 30000 int
#define NEVS_OFF  739464      // 480000 f32
#define NVSC_OFF  1219464     // 9600000 halfs
#define NTOT      6019464     // floats (~24.1 MB)

#define INV_SQRT8  0.35355339059327376f
#define SIG_SS     0.02209708691207961f
#define SIG_UU     0.01804219591217582f
#define SIG_SU     0.02209708691207961f
#define SIG_US     0.03125f
#define D0S        0.08838834764831845f
#define D1S        0.10206207261596575f

// single-wave block: HW executes a wave's DS ops in order; this only pins
// compile-time ordering (no s_barrier, no waitcnt drain). r13-verified.
#define WBAR() __builtin_amdgcn_wave_barrier()

typedef _Float16 half2v __attribute__((ext_vector_type(2)));
typedef _Float16 f16x4  __attribute__((ext_vector_type(4)));
typedef _Float16 f16x8  __attribute__((ext_vector_type(8)));
typedef float    f32x4  __attribute__((ext_vector_type(4)));

__device__ __forceinline__ float fdot2(half2v a, half2v b, float c) {
    return __builtin_amdgcn_fdot2(a, b, c, false);
}

// ---------- fused prep: weight pack (0..17) + g vectors (18..135) + edge hist (136..)
__global__ __launch_bounds__(TPB) void prep_all(
    const float* __restrict__ x, const int* __restrict__ ei,
    const float* __restrict__ wq0, const float* __restrict__ wq1,
    const float* __restrict__ wk1, const float* __restrict__ wk2,
    const float* __restrict__ wv1, const float* __restrict__ wv2,
    const float* __restrict__ wd0, const float* __restrict__ wd1,
    half2v* __restrict__ w1pk, half2v* __restrict__ w1pv,
    _Float16* __restrict__ w2fk, _Float16* __restrict__ w2fv,
    float* __restrict__ g, int* __restrict__ cnt)
{
    const int b = blockIdx.x;
    if (b < 18) {
        int tid = b * TPB + threadIdx.x;   // 4608 exactly
        {
            int p = tid / 2304, rem = tid % 2304;
            int fg = rem >> 6, l = rem & 63;
            int t = fg >> 1, s = fg & 1;
            int kbase = s * 32 + (l >> 4) * 8;
            int m = t * 16 + (l & 15);
            float sig = (m < 128) ? SIG_SS : (m < 192) ? SIG_UU
                      : (m < 256) ? SIG_SU : SIG_US;
            const float* W2 = p ? wv2 : wk2;
            _Float16* dst = (p ? w2fv : w2fk) + (size_t)(fg * 64 + l) * 8;
#pragma unroll
            for (int jj = 0; jj < 8; ++jj)
                dst[jj] = (_Float16)(W2[(size_t)(kbase + jj) * 288 + m] * sig);
        }
        if (tid < 512) {
            int hh = tid >> 3, a2 = tid & 7;
            w1pk[tid] = half2v{(_Float16)(wk1[(2 * a2) * 64 + hh] * 0.25f),
                               (_Float16)(wk1[(2 * a2 + 1) * 64 + hh] * 0.25f)};
            w1pv[tid] = half2v{(_Float16)(wv1[(2 * a2) * 64 + hh] * 0.25f),
                               (_Float16)(wv1[(2 * a2 + 1) * 64 + hh] * 0.25f)};
        }
    } else if (b < 136) {
        // ---- per-node g = Wd-folded q (r12-verified) ----
        int n = (b - 18) * TPB + threadIdx.x;
        if (n >= NN) return;
        const float* xr = x + (size_t)n * 40;
        float* o = g + (size_t)n * 20;
        float q0[8];
#pragma unroll
        for (int bb = 0; bb < 8; ++bb) {
            float acc = 0.f;
#pragma unroll
            for (int a = 0; a < 16; ++a) acc += xr[a] * wq0[a * 8 + bb];
            q0[bb] = acc * 0.25f;
        }
#pragma unroll
        for (int bb = 0; bb < 8; ++bb) {
            float acc = 0.f;
#pragma unroll
            for (int a = 0; a < 8; ++a) acc += q0[a] * wd0[a * 8 + bb];
            o[bb] = acc * D0S;
        }
        float q1[4][3];
#pragma unroll
        for (int bb = 0; bb < 4; ++bb)
#pragma unroll
            for (int c = 0; c < 3; ++c) {
                float acc = 0.f;
#pragma unroll
                for (int a = 0; a < 8; ++a) acc += xr[16 + a * 3 + c] * wq1[a * 4 + bb];
                q1[bb][c] = acc * INV_SQRT8;
            }
#pragma unroll
        for (int bb = 0; bb < 4; ++bb)
#pragma unroll
            for (int c = 0; c < 3; ++c) {
                float acc = 0.f;
#pragma unroll
                for (int a = 0; a < 4; ++a) acc += q1[a][c] * wd1[a * 4 + bb];
                o[8 + bb * 3 + c] = acc * D1S;
            }
    } else {
        // ---- edge histogram (cnt pre-zeroed by memset) ----
        int e = (b - 136) * TPB + threadIdx.x;   // 1875 blocks, exact
        atomicAdd(cnt + ei[NE + e], 1);
    }
}

// ---------- parallel order-free scan: block-local prefix + atomic base ----------
// Bases non-monotonic across blocks; CSR only needs disjoint contiguous segments
// (node_gather reads cnt[j] for lengths, never offs[j+1]-offs[j]).
__global__ __launch_bounds__(TPB) void scan_blk(const int* __restrict__ cnt,
                                                int* __restrict__ offs,
                                                int* __restrict__ base)
{
    __shared__ int sdata[TPB];
    __shared__ int bbase;
    const int t = threadIdx.x;
    const int idx = blockIdx.x * TPB + t;
    const int v = (idx < NN) ? cnt[idx] : 0;
    sdata[t] = v;
    __syncthreads();
    for (int off = 1; off < TPB; off <<= 1) {
        int u = (t >= off) ? sdata[t - off] : 0;
        __syncthreads();
        sdata[t] += u;
        __syncthreads();
    }
    if (t == TPB - 1) bbase = atomicAdd(base, sdata[TPB - 1]);
    __syncthreads();
    if (idx < NN) offs[idx] = bbase + sdata[t] - v;   // exclusive within block
}

// ---------- fused k+v edge kernel ----------
// r17: r16 spilled (WRITE_SIZE 76MB -> 1.8GB scratch). Fixes:
//  (a) xr[40] reloaded per epilogue (not held across V GEMM) — x is cache-hot;
//  (b) MFMA acc scoped PER OUTPUT TILE (dump right after its 2 MFMAs):
//      live accumulators ~16 regs instead of 72.
// Keeps r16 wins: register-resident B fragments (no h staging, no sh_hv),
// shfl-based d-reduce + pe broadcast, g[j] prefetch. LDS 9728 B -> 16 blk/CU.
__global__ __launch_bounds__(ETPB, 4) void edge_fused(
    const float* __restrict__ x, const int* __restrict__ ei,
    const float* __restrict__ eattr, const float* __restrict__ emb,
    const float* __restrict__ el,
    const half2v* __restrict__ w1pk, const f16x8* __restrict__ w2fk,
    const half2v* __restrict__ w1pv, const f16x8* __restrict__ w2fv,
    const float* __restrict__ gn, const int* __restrict__ offs,
    int* __restrict__ c2, float* __restrict__ Z,
    float* __restrict__ evs, _Float16* __restrict__ vsc)
{
    __shared__ __align__(16) _Float16 sh_R[16][292];  // R dumps only

    const int l = threadIdx.x;            // single wave
    const int q = l >> 4, n = l & 15;
    const int e = blockIdx.x * 16 + n;
    const int i = ei[e];
    const int j = ei[NE + e];
    const float4 ea = *(const float4*)(eattr + (size_t)e * 4);
    const float y0 = ea.x, y1x = ea.y, y1y = ea.z, y1z = ea.w;
    const int b0 = (q < 2) ? (4 * q) : (2 * (q - 2));
    const float len = el[e];

    // in-kernel rank (CSR slot); issued first so atomic latency hides under h
    int pe0 = 0;
    if (l < 16) pe0 = offs[j] + atomicAdd(c2 + j, 1);

    // ---- both hidden layers; B fragments register-resident ----
    // thread (q,n) computes k in {8q..8q+7} (B0) and {32+8q..32+8q+7} (B1),
    // which is exactly the 16x16x32 MFMA B-lane-layout for lane l = 16q+n.
    f16x8 Bk0, Bk1, Bv0, Bv1;
    {
        half2v em2[8];
        const float4* ep = (const float4*)(emb + (size_t)e * 16);
#pragma unroll
        for (int p = 0; p < 4; ++p) {
            float4 v = ep[p];
            em2[2 * p]     = half2v{(_Float16)v.x, (_Float16)v.y};
            em2[2 * p + 1] = half2v{(_Float16)v.z, (_Float16)v.w};
        }
#pragma unroll
        for (int hf = 0; hf < 2; ++hf) {
            f16x8 hk, hv;
#pragma unroll
            for (int ii = 0; ii < 8; ++ii) {
                const int k = hf * 32 + q * 8 + ii;
                const half2v* wrk = w1pk + (size_t)k * 8;
                const half2v* wrv = w1pv + (size_t)k * 8;
                float a0 = 0.f, a1 = 0.f, c0 = 0.f, c1 = 0.f;
#pragma unroll
                for (int a2 = 0; a2 < 4; ++a2) {
                    a0 = fdot2(em2[2 * a2],     wrk[2 * a2],     a0);
                    a1 = fdot2(em2[2 * a2 + 1], wrk[2 * a2 + 1], a1);
                    c0 = fdot2(em2[2 * a2],     wrv[2 * a2],     c0);
                    c1 = fdot2(em2[2 * a2 + 1], wrv[2 * a2 + 1], c1);
                }
                const float zk = a0 + a1, zv = c0 + c1;
                hk[ii] = (_Float16)(zk * __builtin_amdgcn_rcpf(1.f + __expf(-zk)));
                hv[ii] = (_Float16)(zv * __builtin_amdgcn_rcpf(1.f + __expf(-zv)));
            }
            if (hf == 0) { Bk0 = hk; Bv0 = hv; } else { Bk1 = hk; Bv1 = hv; }
        }
    }

    // ---- prefetch g[j] slice needed by this thread's k-epilogue b-slice ----
    float gjv[6];
    {
        const float* gj = gn + (size_t)j * 20;
        if (q < 2) {
            float4 t4 = *(const float4*)(gj + b0);
            gjv[0] = t4.x; gjv[1] = t4.y; gjv[2] = t4.z; gjv[3] = t4.w;
            gjv[4] = 0.f;  gjv[5] = 0.f;
        } else {
            const float* gr = gj + 8 + b0 * 3;
#pragma unroll
            for (int r = 0; r < 6; ++r) gjv[r] = gr[r];
        }
    }

    // ================= K GEMM (B from registers; acc scoped per tile) =======
    {
#pragma unroll
        for (int t = 0; t < 18; ++t) {
            f16x8 A0 = w2fk[(t * 2 + 0) * 64 + l];
            f16x8 A1 = w2fk[(t * 2 + 1) * 64 + l];
            f32x4 acc = f32x4{0.f, 0.f, 0.f, 0.f};
            acc = __builtin_amdgcn_mfma_f32_16x16x32_f16(A0, Bk0, acc, 0, 0, 0);
            acc = __builtin_amdgcn_mfma_f32_16x16x32_f16(A1, Bk1, acc, 0, 0, 0);
            f16x4 rv = {(_Float16)acc[0], (_Float16)acc[1],
                        (_Float16)acc[2], (_Float16)acc[3]};
            *(f16x4*)&sh_R[n][t * 16 + 4 * q] = rv;
        }
    }
    WBAR();

    // ---- k epilogue: score partials (b-sliced; Wd pre-folded into g) ----
    float pd = 0.f;
    {
        float xr[40];
        const float4* xp = (const float4*)(x + (size_t)i * 40);
#pragma unroll
        for (int p = 0; p < 10; ++p) {
            float4 v = xp[p];
            xr[4 * p] = v.x; xr[4 * p + 1] = v.y;
            xr[4 * p + 2] = v.z; xr[4 * p + 3] = v.w;
        }
        if (q < 2) {
            float ssv[4] = {0.f, 0.f, 0.f, 0.f};
            float uuv[4] = {0.f, 0.f, 0.f, 0.f};
#pragma unroll
            for (int a = 0; a < 16; ++a) {
                const f16x4 rv = *(const f16x4*)&sh_R[n][a * 8 + b0];
#pragma unroll
                for (int r = 0; r < 4; ++r) ssv[r] += xr[a] * (float)rv[r];
            }
#pragma unroll
            for (int a = 0; a < 8; ++a) {
                const float xy = xr[16 + a * 3] * y1x + xr[17 + a * 3] * y1y
                               + xr[18 + a * 3] * y1z;
                const f16x4 rv = *(const f16x4*)&sh_R[n][128 + a * 8 + b0];
#pragma unroll
                for (int r = 0; r < 4; ++r) uuv[r] += xy * (float)rv[r];
            }
#pragma unroll
            for (int r = 0; r < 4; ++r)
                pd += (y0 * ssv[r] + uuv[r]) * gjv[r];
        } else {
            float suv[2] = {0.f, 0.f};
            float usv[2][3] = {{0.f, 0.f, 0.f}, {0.f, 0.f, 0.f}};
#pragma unroll
            for (int a = 0; a < 16; ++a) {
                const half2v rv = *(const half2v*)&sh_R[n][192 + a * 4 + b0];
                suv[0] += xr[a] * (float)rv[0];
                suv[1] += xr[a] * (float)rv[1];
            }
#pragma unroll
            for (int a = 0; a < 8; ++a) {
                const half2v rv = *(const half2v*)&sh_R[n][256 + a * 4 + b0];
#pragma unroll
                for (int bb = 0; bb < 2; ++bb) {
                    const float wv = (float)rv[bb];
                    usv[bb][0] += xr[16 + a * 3] * wv;
                    usv[bb][1] += xr[17 + a * 3] * wv;
                    usv[bb][2] += xr[18 + a * 3] * wv;
                }
            }
#pragma unroll
            for (int bb = 0; bb < 2; ++bb) {
                const float k1x = suv[bb] * y1x + y0 * usv[bb][0];
                const float k1y = suv[bb] * y1y + y0 * usv[bb][1];
                const float k1z = suv[bb] * y1z + y0 * usv[bb][2];
                pd += k1x * gjv[bb * 3] + k1y * gjv[bb * 3 + 1] + k1z * gjv[bb * 3 + 2];
            }
        }
    }
    // cross-q reduce (lanes 16q+n): no LDS
    pd += __shfl_xor(pd, 16);
    pd += __shfl_xor(pd, 32);
    const int pe = __shfl(pe0, n);   // broadcast CSR slot from lane n
    if (l < 16) {
        const float tt = 10.f * (1.f - len / 3.15f);
        float cut = 0.f;
        if (tt > 0.f) cut = __expf(-1.f / fmaxf(tt, 1e-6f));
        const float ev = cut * __expf(pd);
        evs[pe] = ev;
        atomicAdd(Z + j, ev);
    }
    WBAR();   // all k-epilogue sh_R reads precede v dump (in-order DS, pinned order)

    // ================= V GEMM (B from registers; acc scoped per tile) =======
    {
#pragma unroll
        for (int t = 0; t < 18; ++t) {
            f16x8 A0 = w2fv[(t * 2 + 0) * 64 + l];
            f16x8 A1 = w2fv[(t * 2 + 1) * 64 + l];
            f32x4 acc = f32x4{0.f, 0.f, 0.f, 0.f};
            acc = __builtin_amdgcn_mfma_f32_16x16x32_f16(A0, Bv0, acc, 0, 0, 0);
            acc = __builtin_amdgcn_mfma_f32_16x16x32_f16(A1, Bv1, acc, 0, 0, 0);
            f16x4 rv = {(_Float16)acc[0], (_Float16)acc[1],
                        (_Float16)acc[2], (_Float16)acc[3]};
            *(f16x4*)&sh_R[n][t * 16 + 4 * q] = rv;
        }
    }
    WBAR();

    // ---- v epilogue: store 20-half record at CSR slot (xr reloaded) ----
    {
        float xr[40];
        const float4* xp = (const float4*)(x + (size_t)i * 40);
#pragma unroll
        for (int p = 0; p < 10; ++p) {
            float4 v = xp[p];
            xr[4 * p] = v.x; xr[4 * p + 1] = v.y;
            xr[4 * p + 2] = v.z; xr[4 * p + 3] = v.w;
        }
        _Float16* rec = vsc + (size_t)pe * 20;
        if (q < 2) {
            float ssv[4] = {0.f, 0.f, 0.f, 0.f};
            float uuv[4] = {0.f, 0.f, 0.f, 0.f};
#pragma unroll
            for (int a = 0; a < 16; ++a) {
                const f16x4 rv = *(const f16x4*)&sh_R[n][a * 8 + b0];
#pragma unroll
                for (int r = 0; r < 4; ++r) ssv[r] += xr[a] * (float)rv[r];
            }
#pragma unroll
            for (int a = 0; a < 8; ++a) {
                const float xy = xr[16 + a * 3] * y1x + xr[17 + a * 3] * y1y
                               + xr[18 + a * 3] * y1z;
                const f16x4 rv = *(const f16x4*)&sh_R[n][128 + a * 8 + b0];
#pragma unroll
                for (int r = 0; r < 4; ++r) uuv[r] += xy * (float)rv[r];
            }
            f16x4 o;
#pragma unroll
            for (int r = 0; r < 4; ++r) o[r] = (_Float16)(y0 * ssv[r] + uuv[r]);
            *(f16x4*)&rec[b0] = o;
        } else {
            float suv[2] = {0.f, 0.f};
            float usv[2][3] = {{0.f, 0.f, 0.f}, {0.f, 0.f, 0.f}};
#pragma unroll
            for (int a = 0; a < 16; ++a) {
                const half2v rv = *(const half2v*)&sh_R[n][192 + a * 4 + b0];
                suv[0] += xr[a] * (float)rv[0];
                suv[1] += xr[a] * (float)rv[1];
            }
#pragma unroll
            for (int a = 0; a < 8; ++a) {
                const half2v rv = *(const half2v*)&sh_R[n][256 + a * 4 + b0];
#pragma unroll
                for (int bb = 0; bb < 2; ++bb) {
                    const float wv = (float)rv[bb];
                    usv[bb][0] += xr[16 + a * 3] * wv;
                    usv[bb][1] += xr[17 + a * 3] * wv;
                    usv[bb][2] += xr[18 + a * 3] * wv;
                }
            }
            float k1v[2][3];
#pragma unroll
            for (int bb = 0; bb < 2; ++bb) {
                k1v[bb][0] = suv[bb] * y1x + y0 * usv[bb][0];
                k1v[bb][1] = suv[bb] * y1y + y0 * usv[bb][1];
                k1v[bb][2] = suv[bb] * y1z + y0 * usv[bb][2];
            }
            const int base = 8 + b0 * 3;
            *(half2v*)&rec[base]     = half2v{(_Float16)k1v[0][0], (_Float16)k1v[0][1]};
            *(half2v*)&rec[base + 2] = half2v{(_Float16)k1v[0][2], (_Float16)k1v[1][0]};
            *(half2v*)&rec[base + 4] = half2v{(_Float16)k1v[1][1], (_Float16)k1v[1][2]};
        }
    }
}

// ---------- node gather: Z precomputed; single weighted pass, zero atomics ----------
__global__ __launch_bounds__(TPB) void node_gather(
    const int* __restrict__ offs, const int* __restrict__ cntp,
    const float* __restrict__ Z,
    const float* __restrict__ evs, const _Float16* __restrict__ vsc,
    float* __restrict__ out)
{
    const int wv = threadIdx.x >> 6, lane = threadIdx.x & 63;
    const int j = blockIdx.x * 4 + wv;
    if (j >= NN) return;
    const int o0 = offs[j], cnt = cntp[j];
    const float zz = Z[j];
    const float invZ = (zz > 0.f) ? (1.f / zz) : 0.f;

    const int g = lane / 20, c = lane % 20;
    float acc = 0.f;
    if (g < 3) {
        for (int t = g; t < cnt; t += 3) {
            const float ev = evs[o0 + t];
            const float wgt = sqrtf(fmaxf(ev * invZ, 0.f));
            acc += wgt * (float)vsc[(size_t)(o0 + t) * 20 + c];
        }
    }
    const float a1 = __shfl(acc, lane + 20);
    const float a2 = __shfl(acc, lane + 40);
    if (lane < 20) out[(size_t)j * 20 + lane] = acc + a1 + a2;
}

extern "C" void kernel_launch(void* const* d_in, const int* in_sizes, int n_in,
                              void* d_out, int out_size, void* d_ws, size_t ws_size,
                              hipStream_t stream)
{
    const float* x     = (const float*)d_in[0];
    const int*   eidx  = (const int*)d_in[1];
    const float* eattr = (const float*)d_in[2];
    const float* emb   = (const float*)d_in[3];
    const float* elen  = (const float*)d_in[4];
    const float* wq0   = (const float*)d_in[5];
    const float* wq1   = (const float*)d_in[6];
    const float* wk1   = (const float*)d_in[7];
    const float* wk2   = (const float*)d_in[8];
    const float* wv1   = (const float*)d_in[9];
    const float* wv2   = (const float*)d_in[10];
    const float* wd0   = (const float*)d_in[11];
    const float* wd1   = (const float*)d_in[12];

    float* ws  = (float*)d_ws;
    float* out = (float*)d_out;

    half2v* w1pk = (half2v*)(ws + NW1K_OFF);
    half2v* w1pv = (half2v*)(ws + NW1V_OFF);
    _Float16* w2fk = (_Float16*)(ws + NW2K_OFF);
    _Float16* w2fv = (_Float16*)(ws + NW2V_OFF);
    int* cnt  = (int*)(ws + NCNT_OFF);
    int* c2   = (int*)(ws + NC2_OFF);
    float* Z  = ws + NZ_OFF;
    int* base = (int*)(ws + NBASE_OFF);
    int* offs = (int*)(ws + NOFF_OFF);
    float* evs = ws + NEVS_OFF;
    _Float16* vsc = (_Float16*)(ws + NVSC_OFF);

    // zero cnt + c2 + Z + base (contiguous) in one memset
    hipMemsetAsync(cnt, 0, (3 * NN + 8) * sizeof(int), stream);

    // prep: weights + g + histogram (1875 hist blocks)
    prep_all<<<136 + NE / TPB, TPB, 0, stream>>>(
        x, eidx, wq0, wq1, wk1, wk2, wv1, wv2, wd0, wd1,
        w1pk, w1pv, w2fk, w2fv, ws + NG_OFF, cnt);

    scan_blk<<<(NN + TPB - 1) / TPB, TPB, 0, stream>>>(cnt, offs, base);

    edge_fused<<<NE / 16, ETPB, 0, stream>>>(
        x, eidx, eattr, emb, elen,
        w1pk, (const f16x8*)w2fk, w1pv, (const f16x8*)w2fv,
        ws + NG_OFF, offs, c2, Z, evs, vsc);

    node_gather<<<(NN + 3) / 4, TPB, 0, stream>>>(offs, cnt, Z, evs, vsc, out);
}

// Round 4
// 513.844 us; speedup vs baseline: 2.0109x; 1.5206x over previous
//
#include <hip/hip_runtime.h>
#include <math.h>

#define NN 30000
#define NE 480000
#define TPB 256
#define ETPB 64

// ---- CSR-path workspace layout (float offsets) ----
// cnt, c2, Z, base are contiguous: zeroed by ONE memset
#define NG_OFF    0           // 600000 g vectors (Wd folded)
#define NW1K_OFF  600000      // 512
#define NW1V_OFF  600512      // 512
#define NW2K_OFF  601024      // 9216
#define NW2V_OFF  610240      // 9216
#define NCNT_OFF  619456      // 30000 int
#define NC2_OFF   649456      // 30000 int
#define NZ_OFF    679456      // 30000 f32
#define NBASE_OFF 709456      // 8 int
#define NOFF_OFF  709464      // 30000 int
#define NEVS_OFF  739464      // 480000 f32
#define NVSC_OFF  1219464     // 9600000 halfs
#define NTOT      6019464     // floats (~24.1 MB)

#define INV_SQRT8  0.35355339059327376f
#define SIG_SS     0.02209708691207961f
#define SIG_UU     0.01804219591217582f
#define SIG_SU     0.02209708691207961f
#define SIG_US     0.03125f
#define D0S        0.08838834764831845f
#define D1S        0.10206207261596575f

// single-wave block: HW executes a wave's DS ops in order; this only pins
// compile-time ordering (no s_barrier, no waitcnt drain). r13-verified.
#define WBAR() __builtin_amdgcn_wave_barrier()

typedef _Float16 half2v __attribute__((ext_vector_type(2)));
typedef _Float16 f16x4  __attribute__((ext_vector_type(4)));
typedef _Float16 f16x8  __attribute__((ext_vector_type(8)));
typedef float    f32x4  __attribute__((ext_vector_type(4)));

__device__ __forceinline__ float fdot2(half2v a, half2v b, float c) {
    return __builtin_amdgcn_fdot2(a, b, c, false);
}

// ---------- fused prep: weight pack (0..17) + g vectors (18..135) + edge hist (136..)
__global__ __launch_bounds__(TPB) void prep_all(
    const float* __restrict__ x, const int* __restrict__ ei,
    const float* __restrict__ wq0, const float* __restrict__ wq1,
    const float* __restrict__ wk1, const float* __restrict__ wk2,
    const float* __restrict__ wv1, const float* __restrict__ wv2,
    const float* __restrict__ wd0, const float* __restrict__ wd1,
    half2v* __restrict__ w1pk, half2v* __restrict__ w1pv,
    _Float16* __restrict__ w2fk, _Float16* __restrict__ w2fv,
    float* __restrict__ g, int* __restrict__ cnt)
{
    const int b = blockIdx.x;
    if (b < 18) {
        int tid = b * TPB + threadIdx.x;   // 4608 exactly
        {
            int p = tid / 2304, rem = tid % 2304;
            int fg = rem >> 6, l = rem & 63;
            int t = fg >> 1, s = fg & 1;
            int kbase = s * 32 + (l >> 4) * 8;
            int m = t * 16 + (l & 15);
            float sig = (m < 128) ? SIG_SS : (m < 192) ? SIG_UU
                      : (m < 256) ? SIG_SU : SIG_US;
            const float* W2 = p ? wv2 : wk2;
            _Float16* dst = (p ? w2fv : w2fk) + (size_t)(fg * 64 + l) * 8;
#pragma unroll
            for (int jj = 0; jj < 8; ++jj)
                dst[jj] = (_Float16)(W2[(size_t)(kbase + jj) * 288 + m] * sig);
        }
        if (tid < 512) {
            int hh = tid >> 3, a2 = tid & 7;
            w1pk[tid] = half2v{(_Float16)(wk1[(2 * a2) * 64 + hh] * 0.25f),
                               (_Float16)(wk1[(2 * a2 + 1) * 64 + hh] * 0.25f)};
            w1pv[tid] = half2v{(_Float16)(wv1[(2 * a2) * 64 + hh] * 0.25f),
                               (_Float16)(wv1[(2 * a2 + 1) * 64 + hh] * 0.25f)};
        }
    } else if (b < 136) {
        // ---- per-node g = Wd-folded q (r12-verified) ----
        int n = (b - 18) * TPB + threadIdx.x;
        if (n >= NN) return;
        const float* xr = x + (size_t)n * 40;
        float* o = g + (size_t)n * 20;
        float q0[8];
#pragma unroll
        for (int bb = 0; bb < 8; ++bb) {
            float acc = 0.f;
#pragma unroll
            for (int a = 0; a < 16; ++a) acc += xr[a] * wq0[a * 8 + bb];
            q0[bb] = acc * 0.25f;
        }
#pragma unroll
        for (int bb = 0; bb < 8; ++bb) {
            float acc = 0.f;
#pragma unroll
            for (int a = 0; a < 8; ++a) acc += q0[a] * wd0[a * 8 + bb];
            o[bb] = acc * D0S;
        }
        float q1[4][3];
#pragma unroll
        for (int bb = 0; bb < 4; ++bb)
#pragma unroll
            for (int c = 0; c < 3; ++c) {
                float acc = 0.f;
#pragma unroll
                for (int a = 0; a < 8; ++a) acc += xr[16 + a * 3 + c] * wq1[a * 4 + bb];
                q1[bb][c] = acc * INV_SQRT8;
            }
#pragma unroll
        for (int bb = 0; bb < 4; ++bb)
#pragma unroll
            for (int c = 0; c < 3; ++c) {
                float acc = 0.f;
#pragma unroll
                for (int a = 0; a < 4; ++a) acc += q1[a][c] * wd1[a * 4 + bb];
                o[8 + bb * 3 + c] = acc * D1S;
            }
    } else {
        // ---- edge histogram (cnt pre-zeroed by memset) ----
        int e = (b - 136) * TPB + threadIdx.x;   // 1875 blocks, exact
        atomicAdd(cnt + ei[NE + e], 1);
    }
}

// ---------- parallel order-free scan: block-local prefix + atomic base ----------
__global__ __launch_bounds__(TPB) void scan_blk(const int* __restrict__ cnt,
                                                int* __restrict__ offs,
                                                int* __restrict__ base)
{
    __shared__ int sdata[TPB];
    __shared__ int bbase;
    const int t = threadIdx.x;
    const int idx = blockIdx.x * TPB + t;
    const int v = (idx < NN) ? cnt[idx] : 0;
    sdata[t] = v;
    __syncthreads();
    for (int off = 1; off < TPB; off <<= 1) {
        int u = (t >= off) ? sdata[t - off] : 0;
        __syncthreads();
        sdata[t] += u;
        __syncthreads();
    }
    if (t == TPB - 1) bbase = atomicAdd(base, sdata[TPB - 1]);
    __syncthreads();
    if (idx < NN) offs[idx] = bbase + sdata[t] - v;   // exclusive within block
}

// ---------- fused k+v edge kernel ----------
// r18 (resubmit; round-3 bench was an infra failure, no verdict).
// a-split epilogues: r17 still spilled ~2.2GB: with launch_bounds(64,4)
// the unified file splits 64 arch + 64 acc; xr[40]-per-thread epilogues can't
// fit 64 arch alongside held Bv frags. Fix: slice epilogues over INPUT a
// (thread q owns s-ch [4q,4q+4) + u-ch [2q,2q+2) -> 10 x floats/thread),
// compute 20 partials over ALL b, cross-q shfl_xor reduce. g streamed, never
// held. Wide ds_read_b128 R reads (row stride 292->296 halfs for 16B align).
// Keeps: register-B fragments, no sh_hv, shfl pe/d, LDS 9472 B.
__global__ __launch_bounds__(ETPB, 4) void edge_fused(
    const float* __restrict__ x, const int* __restrict__ ei,
    const float* __restrict__ eattr, const float* __restrict__ emb,
    const float* __restrict__ el,
    const half2v* __restrict__ w1pk, const f16x8* __restrict__ w2fk,
    const half2v* __restrict__ w1pv, const f16x8* __restrict__ w2fv,
    const float* __restrict__ gn, const int* __restrict__ offs,
    int* __restrict__ c2, float* __restrict__ Z,
    float* __restrict__ evs, _Float16* __restrict__ vsc)
{
    __shared__ __align__(16) _Float16 sh_R[16][296];  // R dumps only (9472 B)

    const int l = threadIdx.x;            // single wave
    const int q = l >> 4, n = l & 15;
    const int e = blockIdx.x * 16 + n;
    const int i = ei[e];
    const int j = ei[NE + e];
    const float4 ea = *(const float4*)(eattr + (size_t)e * 4);
    const float y0 = ea.x, y1x = ea.y, y1y = ea.z, y1z = ea.w;
    const float len = el[e];

    // in-kernel rank (CSR slot); only q==0 lanes own an edge slot
    int pe0 = 0;
    if (l < 16) pe0 = offs[j] + atomicAdd(c2 + j, 1);

    // ---- both hidden layers; B fragments register-resident ----
    // thread (q,n) computes k in {8q..8q+7} (B0) and {32+8q..+7} (B1) =
    // exactly the 16x16x32 MFMA B-lane-layout for lane l = 16q+n (r16/r17-verified).
    f16x8 Bk0, Bk1, Bv0, Bv1;
    {
        half2v em2[8];
        const float4* ep = (const float4*)(emb + (size_t)e * 16);
#pragma unroll
        for (int p = 0; p < 4; ++p) {
            float4 v = ep[p];
            em2[2 * p]     = half2v{(_Float16)v.x, (_Float16)v.y};
            em2[2 * p + 1] = half2v{(_Float16)v.z, (_Float16)v.w};
        }
#pragma unroll
        for (int hf = 0; hf < 2; ++hf) {
            f16x8 hk, hv;
#pragma unroll
            for (int ii = 0; ii < 8; ++ii) {
                const int k = hf * 32 + q * 8 + ii;
                const half2v* wrk = w1pk + (size_t)k * 8;
                const half2v* wrv = w1pv + (size_t)k * 8;
                float a0 = 0.f, a1 = 0.f, c0 = 0.f, c1 = 0.f;
#pragma unroll
                for (int a2 = 0; a2 < 4; ++a2) {
                    a0 = fdot2(em2[2 * a2],     wrk[2 * a2],     a0);
                    a1 = fdot2(em2[2 * a2 + 1], wrk[2 * a2 + 1], a1);
                    c0 = fdot2(em2[2 * a2],     wrv[2 * a2],     c0);
                    c1 = fdot2(em2[2 * a2 + 1], wrv[2 * a2 + 1], c1);
                }
                const float zk = a0 + a1, zv = c0 + c1;
                hk[ii] = (_Float16)(zk * __builtin_amdgcn_rcpf(1.f + __expf(-zk)));
                hv[ii] = (_Float16)(zv * __builtin_amdgcn_rcpf(1.f + __expf(-zv)));
            }
            if (hf == 0) { Bk0 = hk; Bv0 = hv; } else { Bk1 = hk; Bv1 = hv; }
        }
    }

    // ---- this thread's x-slice: s-channels [4q,4q+4), u-channels [2q,2q+2) ----
    float xs[4];
    float xu[2][3];
    {
        const float* xb = x + (size_t)i * 40;
        float4 s4 = *(const float4*)(xb + 4 * q);         // 16B aligned
        xs[0] = s4.x; xs[1] = s4.y; xs[2] = s4.z; xs[3] = s4.w;
        const float* ub = xb + 16 + 6 * q;                // even idx -> 8B aligned
        float2 u0 = *(const float2*)(ub);
        float2 u1 = *(const float2*)(ub + 2);
        float2 u2 = *(const float2*)(ub + 4);
        xu[0][0] = u0.x; xu[0][1] = u0.y; xu[0][2] = u1.x;
        xu[1][0] = u1.y; xu[1][1] = u2.x; xu[1][2] = u2.y;
    }

    // partial-tensor-product over this thread's a-slice, all 20 b-outputs.
    // P0[b] = y0*sum_{a in Sq} xs_a*Rss[a][b] + sum_{a in Uq} (xu_a.y1)*Ruu[a][b]
    // P1[b][c] = y1[c]*sum_{Sq} xs_a*Rsu[a][b] + y0*sum_{Uq} xu[a][c]*Rus[a][b]
    auto P_COMPUTE = [&](float P0[8], float P1[4][3]) {
#pragma unroll
        for (int b = 0; b < 8; ++b) P0[b] = 0.f;
#pragma unroll
        for (int d = 0; d < 4; ++d) {
            const f16x8 rv = *(const f16x8*)&sh_R[n][(4 * q + d) * 8];
            const float xv = xs[d];
#pragma unroll
            for (int b = 0; b < 8; ++b) P0[b] += xv * (float)rv[b];
        }
#pragma unroll
        for (int b = 0; b < 8; ++b) P0[b] *= y0;
#pragma unroll
        for (int d = 0; d < 2; ++d) {
            const f16x8 rv = *(const f16x8*)&sh_R[n][128 + (2 * q + d) * 8];
            const float xy = xu[d][0] * y1x + xu[d][1] * y1y + xu[d][2] * y1z;
#pragma unroll
            for (int b = 0; b < 8; ++b) P0[b] += xy * (float)rv[b];
        }
        float su[4] = {0.f, 0.f, 0.f, 0.f};
#pragma unroll
        for (int d = 0; d < 4; ++d) {
            const f16x4 rv = *(const f16x4*)&sh_R[n][192 + (4 * q + d) * 4];
            const float xv = xs[d];
#pragma unroll
            for (int b = 0; b < 4; ++b) su[b] += xv * (float)rv[b];
        }
        float us[4][3] = {{0.f,0.f,0.f},{0.f,0.f,0.f},{0.f,0.f,0.f},{0.f,0.f,0.f}};
#pragma unroll
        for (int d = 0; d < 2; ++d) {
            const f16x4 rv = *(const f16x4*)&sh_R[n][256 + (2 * q + d) * 4];
#pragma unroll
            for (int b = 0; b < 4; ++b) {
                const float wv = (float)rv[b];
                us[b][0] += xu[d][0] * wv;
                us[b][1] += xu[d][1] * wv;
                us[b][2] += xu[d][2] * wv;
            }
        }
#pragma unroll
        for (int b = 0; b < 4; ++b) {
            P1[b][0] = su[b] * y1x + y0 * us[b][0];
            P1[b][1] = su[b] * y1y + y0 * us[b][1];
            P1[b][2] = su[b] * y1z + y0 * us[b][2];
        }
    };

    // ================= K GEMM (B from registers; acc scoped per tile) =======
    {
#pragma unroll
        for (int t = 0; t < 18; ++t) {
            f16x8 A0 = w2fk[(t * 2 + 0) * 64 + l];
            f16x8 A1 = w2fk[(t * 2 + 1) * 64 + l];
            f32x4 acc = f32x4{0.f, 0.f, 0.f, 0.f};
            acc = __builtin_amdgcn_mfma_f32_16x16x32_f16(A0, Bk0, acc, 0, 0, 0);
            acc = __builtin_amdgcn_mfma_f32_16x16x32_f16(A1, Bk1, acc, 0, 0, 0);
            f16x4 rv = {(_Float16)acc[0], (_Float16)acc[1],
                        (_Float16)acc[2], (_Float16)acc[3]};
            *(f16x4*)&sh_R[n][t * 16 + 4 * q] = rv;
        }
    }
    WBAR();

    // ---- k epilogue: score via partials, g streamed, scalar shfl reduce ----
    {
        float P0[8], P1[4][3];
        P_COMPUTE(P0, P1);
        const float* gj = gn + (size_t)j * 20;
        float pd = 0.f;
        {
            float4 ga = *(const float4*)(gj);
            float4 gb = *(const float4*)(gj + 4);
            pd += P0[0] * ga.x + P0[1] * ga.y + P0[2] * ga.z + P0[3] * ga.w;
            pd += P0[4] * gb.x + P0[5] * gb.y + P0[6] * gb.z + P0[7] * gb.w;
        }
        {
            float4 ga = *(const float4*)(gj + 8);
            float4 gb = *(const float4*)(gj + 12);
            float4 gc = *(const float4*)(gj + 16);
            pd += P1[0][0] * ga.x + P1[0][1] * ga.y + P1[0][2] * ga.z
                + P1[1][0] * ga.w;
            pd += P1[1][1] * gb.x + P1[1][2] * gb.y + P1[2][0] * gb.z
                + P1[2][1] * gb.w;
            pd += P1[2][2] * gc.x + P1[3][0] * gc.y + P1[3][1] * gc.z
                + P1[3][2] * gc.w;
        }
        pd += __shfl_xor(pd, 16);
        pd += __shfl_xor(pd, 32);
        if (l < 16) {
            const float tt = 10.f * (1.f - len / 3.15f);
            float cut = 0.f;
            if (tt > 0.f) cut = __expf(-1.f / fmaxf(tt, 1e-6f));
            const float ev = cut * __expf(pd);
            evs[pe0] = ev;
            atomicAdd(Z + j, ev);
        }
    }
    WBAR();   // all k-epilogue sh_R reads precede v dump (in-order DS, pinned order)

    // ================= V GEMM (B from registers; acc scoped per tile) =======
    {
#pragma unroll
        for (int t = 0; t < 18; ++t) {
            f16x8 A0 = w2fv[(t * 2 + 0) * 64 + l];
            f16x8 A1 = w2fv[(t * 2 + 1) * 64 + l];
            f32x4 acc = f32x4{0.f, 0.f, 0.f, 0.f};
            acc = __builtin_amdgcn_mfma_f32_16x16x32_f16(A0, Bv0, acc, 0, 0, 0);
            acc = __builtin_amdgcn_mfma_f32_16x16x32_f16(A1, Bv1, acc, 0, 0, 0);
            f16x4 rv = {(_Float16)acc[0], (_Float16)acc[1],
                        (_Float16)acc[2], (_Float16)acc[3]};
            *(f16x4*)&sh_R[n][t * 16 + 4 * q] = rv;
        }
    }
    WBAR();

    // ---- v epilogue: partials -> 20-value cross-q reduce -> q==0 stores ----
    {
        float P0[8], P1[4][3];
        P_COMPUTE(P0, P1);
#pragma unroll
        for (int b = 0; b < 8; ++b) {
            P0[b] += __shfl_xor(P0[b], 16);
            P0[b] += __shfl_xor(P0[b], 32);
        }
#pragma unroll
        for (int b = 0; b < 4; ++b)
#pragma unroll
            for (int c = 0; c < 3; ++c) {
                P1[b][c] += __shfl_xor(P1[b][c], 16);
                P1[b][c] += __shfl_xor(P1[b][c], 32);
            }
        if (l < 16) {
            _Float16* rec = vsc + (size_t)pe0 * 20;   // 40B records, 8B aligned
            f16x4 o0 = {(_Float16)P0[0], (_Float16)P0[1],
                        (_Float16)P0[2], (_Float16)P0[3]};
            f16x4 o1 = {(_Float16)P0[4], (_Float16)P0[5],
                        (_Float16)P0[6], (_Float16)P0[7]};
            f16x4 o2 = {(_Float16)P1[0][0], (_Float16)P1[0][1],
                        (_Float16)P1[0][2], (_Float16)P1[1][0]};
            f16x4 o3 = {(_Float16)P1[1][1], (_Float16)P1[1][2],
                        (_Float16)P1[2][0], (_Float16)P1[2][1]};
            f16x4 o4 = {(_Float16)P1[2][2], (_Float16)P1[3][0],
                        (_Float16)P1[3][1], (_Float16)P1[3][2]};
            *(f16x4*)&rec[0]  = o0;
            *(f16x4*)&rec[4]  = o1;
            *(f16x4*)&rec[8]  = o2;
            *(f16x4*)&rec[12] = o3;
            *(f16x4*)&rec[16] = o4;
        }
    }
}

// ---------- node gather: Z precomputed; single weighted pass, zero atomics ----------
__global__ __launch_bounds__(TPB) void node_gather(
    const int* __restrict__ offs, const int* __restrict__ cntp,
    const float* __restrict__ Z,
    const float* __restrict__ evs, const _Float16* __restrict__ vsc,
    float* __restrict__ out)
{
    const int wv = threadIdx.x >> 6, lane = threadIdx.x & 63;
    const int j = blockIdx.x * 4 + wv;
    if (j >= NN) return;
    const int o0 = offs[j], cnt = cntp[j];
    const float zz = Z[j];
    const float invZ = (zz > 0.f) ? (1.f / zz) : 0.f;

    const int g = lane / 20, c = lane % 20;
    float acc = 0.f;
    if (g < 3) {
        for (int t = g; t < cnt; t += 3) {
            const float ev = evs[o0 + t];
            const float wgt = sqrtf(fmaxf(ev * invZ, 0.f));
            acc += wgt * (float)vsc[(size_t)(o0 + t) * 20 + c];
        }
    }
    const float a1 = __shfl(acc, lane + 20);
    const float a2 = __shfl(acc, lane + 40);
    if (lane < 20) out[(size_t)j * 20 + lane] = acc + a1 + a2;
}

extern "C" void kernel_launch(void* const* d_in, const int* in_sizes, int n_in,
                              void* d_out, int out_size, void* d_ws, size_t ws_size,
                              hipStream_t stream)
{
    const float* x     = (const float*)d_in[0];
    const int*   eidx  = (const int*)d_in[1];
    const float* eattr = (const float*)d_in[2];
    const float* emb   = (const float*)d_in[3];
    const float* elen  = (const float*)d_in[4];
    const float* wq0   = (const float*)d_in[5];
    const float* wq1   = (const float*)d_in[6];
    const float* wk1   = (const float*)d_in[7];
    const float* wk2   = (const float*)d_in[8];
    const float* wv1   = (const float*)d_in[9];
    const float* wv2   = (const float*)d_in[10];
    const float* wd0   = (const float*)d_in[11];
    const float* wd1   = (const float*)d_in[12];

    float* ws  = (float*)d_ws;
    float* out = (float*)d_out;

    half2v* w1pk = (half2v*)(ws + NW1K_OFF);
    half2v* w1pv = (half2v*)(ws + NW1V_OFF);
    _Float16* w2fk = (_Float16*)(ws + NW2K_OFF);
    _Float16* w2fv = (_Float16*)(ws + NW2V_OFF);
    int* cnt  = (int*)(ws + NCNT_OFF);
    int* c2   = (int*)(ws + NC2_OFF);
    float* Z  = ws + NZ_OFF;
    int* base = (int*)(ws + NBASE_OFF);
    int* offs = (int*)(ws + NOFF_OFF);
    float* evs = ws + NEVS_OFF;
    _Float16* vsc = (_Float16*)(ws + NVSC_OFF);

    // zero cnt + c2 + Z + base (contiguous) in one memset
    hipMemsetAsync(cnt, 0, (3 * NN + 8) * sizeof(int), stream);

    // prep: weights + g + histogram (1875 hist blocks)
    prep_all<<<136 + NE / TPB, TPB, 0, stream>>>(
        x, eidx, wq0, wq1, wk1, wk2, wv1, wv2, wd0, wd1,
        w1pk, w1pv, w2fk, w2fv, ws + NG_OFF, cnt);

    scan_blk<<<(NN + TPB - 1) / TPB, TPB, 0, stream>>>(cnt, offs, base);

    edge_fused<<<NE / 16, ETPB, 0, stream>>>(
        x, eidx, eattr, emb, elen,
        w1pk, (const f16x8*)w2fk, w1pv, (const f16x8*)w2fv,
        ws + NG_OFF, offs, c2, Z, evs, vsc);

    node_gather<<<(NN + 3) / 4, TPB, 0, stream>>>(offs, cnt, Z, evs, vsc, out);
}

// Round 5
// 320.660 us; speedup vs baseline: 3.2224x; 1.6025x over previous
//
#include <hip/hip_runtime.h>
#include <math.h>

#define NN 30000
#define NE 480000
#define TPB 256
#define ETPB 64

// ---- CSR-path workspace layout (float offsets) ----
// cnt, c2, Z, base are contiguous: zeroed by ONE memset
#define NG_OFF    0           // 600000 g vectors (Wd folded)
#define NW1K_OFF  600000      // 512
#define NW1V_OFF  600512      // 512
#define NW2K_OFF  601024      // 9216
#define NW2V_OFF  610240      // 9216
#define NCNT_OFF  619456      // 30000 int
#define NC2_OFF   649456      // 30000 int
#define NZ_OFF    679456      // 30000 f32
#define NBASE_OFF 709456      // 8 int
#define NOFF_OFF  709464      // 30000 int
#define NEVS_OFF  739464      // 480000 f32
#define NVSC_OFF  1219464     // 9600000 halfs
#define NTOT      6019464     // floats (~24.1 MB)

#define INV_SQRT8  0.35355339059327376f
#define SIG_SS     0.02209708691207961f
#define SIG_UU     0.01804219591217582f
#define SIG_SU     0.02209708691207961f
#define SIG_US     0.03125f
#define D0S        0.08838834764831845f
#define D1S        0.10206207261596575f

// single-wave block: HW executes a wave's DS ops in order; this only pins
// compile-time ordering (no s_barrier, no waitcnt drain). r13-verified.
#define WBAR() __builtin_amdgcn_wave_barrier()

typedef _Float16 half2v __attribute__((ext_vector_type(2)));
typedef _Float16 f16x4  __attribute__((ext_vector_type(4)));
typedef _Float16 f16x8  __attribute__((ext_vector_type(8)));
typedef float    f32x4  __attribute__((ext_vector_type(4)));

__device__ __forceinline__ float fdot2(half2v a, half2v b, float c) {
    return __builtin_amdgcn_fdot2(a, b, c, false);
}

// ---------- fused prep: weight pack (0..17) + g vectors (18..135) + edge hist (136..)
__global__ __launch_bounds__(TPB) void prep_all(
    const float* __restrict__ x, const int* __restrict__ ei,
    const float* __restrict__ wq0, const float* __restrict__ wq1,
    const float* __restrict__ wk1, const float* __restrict__ wk2,
    const float* __restrict__ wv1, const float* __restrict__ wv2,
    const float* __restrict__ wd0, const float* __restrict__ wd1,
    half2v* __restrict__ w1pk, half2v* __restrict__ w1pv,
    _Float16* __restrict__ w2fk, _Float16* __restrict__ w2fv,
    float* __restrict__ g, int* __restrict__ cnt)
{
    const int b = blockIdx.x;
    if (b < 18) {
        int tid = b * TPB + threadIdx.x;   // 4608 exactly
        {
            int p = tid / 2304, rem = tid % 2304;
            int fg = rem >> 6, l = rem & 63;
            int t = fg >> 1, s = fg & 1;
            int kbase = s * 32 + (l >> 4) * 8;
            int m = t * 16 + (l & 15);
            float sig = (m < 128) ? SIG_SS : (m < 192) ? SIG_UU
                      : (m < 256) ? SIG_SU : SIG_US;
            const float* W2 = p ? wv2 : wk2;
            _Float16* dst = (p ? w2fv : w2fk) + (size_t)(fg * 64 + l) * 8;
#pragma unroll
            for (int jj = 0; jj < 8; ++jj)
                dst[jj] = (_Float16)(W2[(size_t)(kbase + jj) * 288 + m] * sig);
        }
        if (tid < 512) {
            int hh = tid >> 3, a2 = tid & 7;
            w1pk[tid] = half2v{(_Float16)(wk1[(2 * a2) * 64 + hh] * 0.25f),
                               (_Float16)(wk1[(2 * a2 + 1) * 64 + hh] * 0.25f)};
            w1pv[tid] = half2v{(_Float16)(wv1[(2 * a2) * 64 + hh] * 0.25f),
                               (_Float16)(wv1[(2 * a2 + 1) * 64 + hh] * 0.25f)};
        }
    } else if (b < 136) {
        // ---- per-node g = Wd-folded q (r12-verified) ----
        int n = (b - 18) * TPB + threadIdx.x;
        if (n >= NN) return;
        const float* xr = x + (size_t)n * 40;
        float* o = g + (size_t)n * 20;
        float q0[8];
#pragma unroll
        for (int bb = 0; bb < 8; ++bb) {
            float acc = 0.f;
#pragma unroll
            for (int a = 0; a < 16; ++a) acc += xr[a] * wq0[a * 8 + bb];
            q0[bb] = acc * 0.25f;
        }
#pragma unroll
        for (int bb = 0; bb < 8; ++bb) {
            float acc = 0.f;
#pragma unroll
            for (int a = 0; a < 8; ++a) acc += q0[a] * wd0[a * 8 + bb];
            o[bb] = acc * D0S;
        }
        float q1[4][3];
#pragma unroll
        for (int bb = 0; bb < 4; ++bb)
#pragma unroll
            for (int c = 0; c < 3; ++c) {
                float acc = 0.f;
#pragma unroll
                for (int a = 0; a < 8; ++a) acc += xr[16 + a * 3 + c] * wq1[a * 4 + bb];
                q1[bb][c] = acc * INV_SQRT8;
            }
#pragma unroll
        for (int bb = 0; bb < 4; ++bb)
#pragma unroll
            for (int c = 0; c < 3; ++c) {
                float acc = 0.f;
#pragma unroll
                for (int a = 0; a < 4; ++a) acc += q1[a][c] * wd1[a * 4 + bb];
                o[8 + bb * 3 + c] = acc * D1S;
            }
    } else {
        // ---- edge histogram (cnt pre-zeroed by memset) ----
        int e = (b - 136) * TPB + threadIdx.x;   // 1875 blocks, exact
        atomicAdd(cnt + ei[NE + e], 1);
    }
}

// ---------- parallel order-free scan: block-local prefix + atomic base ----------
__global__ __launch_bounds__(TPB) void scan_blk(const int* __restrict__ cnt,
                                                int* __restrict__ offs,
                                                int* __restrict__ base)
{
    __shared__ int sdata[TPB];
    __shared__ int bbase;
    const int t = threadIdx.x;
    const int idx = blockIdx.x * TPB + t;
    const int v = (idx < NN) ? cnt[idx] : 0;
    sdata[t] = v;
    __syncthreads();
    for (int off = 1; off < TPB; off <<= 1) {
        int u = (t >= off) ? sdata[t - off] : 0;
        __syncthreads();
        sdata[t] += u;
        __syncthreads();
    }
    if (t == TPB - 1) bbase = atomicAdd(base, sdata[TPB - 1]);
    __syncthreads();
    if (idx < NN) offs[idx] = bbase + sdata[t] - v;   // exclusive within block
}

// ---------- fused k+v edge kernel ----------
// r19: SAME structure as r18 (a-split epilogues, register-B fragments).
// ONE change: __launch_bounds__(64,4) -> (64,2). Theory: the 128-reg unified
// cap (512/4) forced a 64-arch split w/ MFMA accum region + pipelined A-loads,
// spilling ~900MB/dispatch (VGPR_Count pinned at 64 across r16-r18 while
// per-thread state shrank). Cap 256 lets the allocator fit (~100-140 total);
// occupancy lands 12-16 blk/CU (LDS 9728B caps 16) >= baseline's 13, minus
// all scratch traffic. Falsifiable: if WRITE_SIZE stays >>100MB, cap theory
// is wrong -> disasm next, no more blind restructures.
__global__ __launch_bounds__(ETPB, 2) void edge_fused(
    const float* __restrict__ x, const int* __restrict__ ei,
    const float* __restrict__ eattr, const float* __restrict__ emb,
    const float* __restrict__ el,
    const half2v* __restrict__ w1pk, const f16x8* __restrict__ w2fk,
    const half2v* __restrict__ w1pv, const f16x8* __restrict__ w2fv,
    const float* __restrict__ gn, const int* __restrict__ offs,
    int* __restrict__ c2, float* __restrict__ Z,
    float* __restrict__ evs, _Float16* __restrict__ vsc)
{
    __shared__ __align__(16) _Float16 sh_R[16][296];  // R dumps only (9472 B)

    const int l = threadIdx.x;            // single wave
    const int q = l >> 4, n = l & 15;
    const int e = blockIdx.x * 16 + n;
    const int i = ei[e];
    const int j = ei[NE + e];
    const float4 ea = *(const float4*)(eattr + (size_t)e * 4);
    const float y0 = ea.x, y1x = ea.y, y1y = ea.z, y1z = ea.w;
    const float len = el[e];

    // in-kernel rank (CSR slot); only q==0 lanes own an edge slot
    int pe0 = 0;
    if (l < 16) pe0 = offs[j] + atomicAdd(c2 + j, 1);

    // ---- both hidden layers; B fragments register-resident ----
    // thread (q,n) computes k in {8q..8q+7} (B0) and {32+8q..+7} (B1) =
    // exactly the 16x16x32 MFMA B-lane-layout for lane l = 16q+n (r16/r17-verified).
    f16x8 Bk0, Bk1, Bv0, Bv1;
    {
        half2v em2[8];
        const float4* ep = (const float4*)(emb + (size_t)e * 16);
#pragma unroll
        for (int p = 0; p < 4; ++p) {
            float4 v = ep[p];
            em2[2 * p]     = half2v{(_Float16)v.x, (_Float16)v.y};
            em2[2 * p + 1] = half2v{(_Float16)v.z, (_Float16)v.w};
        }
#pragma unroll
        for (int hf = 0; hf < 2; ++hf) {
            f16x8 hk, hv;
#pragma unroll
            for (int ii = 0; ii < 8; ++ii) {
                const int k = hf * 32 + q * 8 + ii;
                const half2v* wrk = w1pk + (size_t)k * 8;
                const half2v* wrv = w1pv + (size_t)k * 8;
                float a0 = 0.f, a1 = 0.f, c0 = 0.f, c1 = 0.f;
#pragma unroll
                for (int a2 = 0; a2 < 4; ++a2) {
                    a0 = fdot2(em2[2 * a2],     wrk[2 * a2],     a0);
                    a1 = fdot2(em2[2 * a2 + 1], wrk[2 * a2 + 1], a1);
                    c0 = fdot2(em2[2 * a2],     wrv[2 * a2],     c0);
                    c1 = fdot2(em2[2 * a2 + 1], wrv[2 * a2 + 1], c1);
                }
                const float zk = a0 + a1, zv = c0 + c1;
                hk[ii] = (_Float16)(zk * __builtin_amdgcn_rcpf(1.f + __expf(-zk)));
                hv[ii] = (_Float16)(zv * __builtin_amdgcn_rcpf(1.f + __expf(-zv)));
            }
            if (hf == 0) { Bk0 = hk; Bv0 = hv; } else { Bk1 = hk; Bv1 = hv; }
        }
    }

    // ---- this thread's x-slice: s-channels [4q,4q+4), u-channels [2q,2q+2) ----
    float xs[4];
    float xu[2][3];
    {
        const float* xb = x + (size_t)i * 40;
        float4 s4 = *(const float4*)(xb + 4 * q);         // 16B aligned
        xs[0] = s4.x; xs[1] = s4.y; xs[2] = s4.z; xs[3] = s4.w;
        const float* ub = xb + 16 + 6 * q;                // even idx -> 8B aligned
        float2 u0 = *(const float2*)(ub);
        float2 u1 = *(const float2*)(ub + 2);
        float2 u2 = *(const float2*)(ub + 4);
        xu[0][0] = u0.x; xu[0][1] = u0.y; xu[0][2] = u1.x;
        xu[1][0] = u1.y; xu[1][1] = u2.x; xu[1][2] = u2.y;
    }

    // partial-tensor-product over this thread's a-slice, all 20 b-outputs.
    // P0[b] = y0*sum_{a in Sq} xs_a*Rss[a][b] + sum_{a in Uq} (xu_a.y1)*Ruu[a][b]
    // P1[b][c] = y1[c]*sum_{Sq} xs_a*Rsu[a][b] + y0*sum_{Uq} xu[a][c]*Rus[a][b]
    auto P_COMPUTE = [&](float P0[8], float P1[4][3]) {
#pragma unroll
        for (int b = 0; b < 8; ++b) P0[b] = 0.f;
#pragma unroll
        for (int d = 0; d < 4; ++d) {
            const f16x8 rv = *(const f16x8*)&sh_R[n][(4 * q + d) * 8];
            const float xv = xs[d];
#pragma unroll
            for (int b = 0; b < 8; ++b) P0[b] += xv * (float)rv[b];
        }
#pragma unroll
        for (int b = 0; b < 8; ++b) P0[b] *= y0;
#pragma unroll
        for (int d = 0; d < 2; ++d) {
            const f16x8 rv = *(const f16x8*)&sh_R[n][128 + (2 * q + d) * 8];
            const float xy = xu[d][0] * y1x + xu[d][1] * y1y + xu[d][2] * y1z;
#pragma unroll
            for (int b = 0; b < 8; ++b) P0[b] += xy * (float)rv[b];
        }
        float su[4] = {0.f, 0.f, 0.f, 0.f};
#pragma unroll
        for (int d = 0; d < 4; ++d) {
            const f16x4 rv = *(const f16x4*)&sh_R[n][192 + (4 * q + d) * 4];
            const float xv = xs[d];
#pragma unroll
            for (int b = 0; b < 4; ++b) su[b] += xv * (float)rv[b];
        }
        float us[4][3] = {{0.f,0.f,0.f},{0.f,0.f,0.f},{0.f,0.f,0.f},{0.f,0.f,0.f}};
#pragma unroll
        for (int d = 0; d < 2; ++d) {
            const f16x4 rv = *(const f16x4*)&sh_R[n][256 + (2 * q + d) * 4];
#pragma unroll
            for (int b = 0; b < 4; ++b) {
                const float wv = (float)rv[b];
                us[b][0] += xu[d][0] * wv;
                us[b][1] += xu[d][1] * wv;
                us[b][2] += xu[d][2] * wv;
            }
        }
#pragma unroll
        for (int b = 0; b < 4; ++b) {
            P1[b][0] = su[b] * y1x + y0 * us[b][0];
            P1[b][1] = su[b] * y1y + y0 * us[b][1];
            P1[b][2] = su[b] * y1z + y0 * us[b][2];
        }
    };

    // ================= K GEMM (B from registers; acc scoped per tile) =======
    {
#pragma unroll
        for (int t = 0; t < 18; ++t) {
            f16x8 A0 = w2fk[(t * 2 + 0) * 64 + l];
            f16x8 A1 = w2fk[(t * 2 + 1) * 64 + l];
            f32x4 acc = f32x4{0.f, 0.f, 0.f, 0.f};
            acc = __builtin_amdgcn_mfma_f32_16x16x32_f16(A0, Bk0, acc, 0, 0, 0);
            acc = __builtin_amdgcn_mfma_f32_16x16x32_f16(A1, Bk1, acc, 0, 0, 0);
            f16x4 rv = {(_Float16)acc[0], (_Float16)acc[1],
                        (_Float16)acc[2], (_Float16)acc[3]};
            *(f16x4*)&sh_R[n][t * 16 + 4 * q] = rv;
        }
    }
    WBAR();

    // ---- k epilogue: score via partials, g streamed, scalar shfl reduce ----
    {
        float P0[8], P1[4][3];
        P_COMPUTE(P0, P1);
        const float* gj = gn + (size_t)j * 20;
        float pd = 0.f;
        {
            float4 ga = *(const float4*)(gj);
            float4 gb = *(const float4*)(gj + 4);
            pd += P0[0] * ga.x + P0[1] * ga.y + P0[2] * ga.z + P0[3] * ga.w;
            pd += P0[4] * gb.x + P0[5] * gb.y + P0[6] * gb.z + P0[7] * gb.w;
        }
        {
            float4 ga = *(const float4*)(gj + 8);
            float4 gb = *(const float4*)(gj + 12);
            float4 gc = *(const float4*)(gj + 16);
            pd += P1[0][0] * ga.x + P1[0][1] * ga.y + P1[0][2] * ga.z
                + P1[1][0] * ga.w;
            pd += P1[1][1] * gb.x + P1[1][2] * gb.y + P1[2][0] * gb.z
                + P1[2][1] * gb.w;
            pd += P1[2][2] * gc.x + P1[3][0] * gc.y + P1[3][1] * gc.z
                + P1[3][2] * gc.w;
        }
        pd += __shfl_xor(pd, 16);
        pd += __shfl_xor(pd, 32);
        if (l < 16) {
            const float tt = 10.f * (1.f - len / 3.15f);
            float cut = 0.f;
            if (tt > 0.f) cut = __expf(-1.f / fmaxf(tt, 1e-6f));
            const float ev = cut * __expf(pd);
            evs[pe0] = ev;
            atomicAdd(Z + j, ev);
        }
    }
    WBAR();   // all k-epilogue sh_R reads precede v dump (in-order DS, pinned order)

    // ================= V GEMM (B from registers; acc scoped per tile) =======
    {
#pragma unroll
        for (int t = 0; t < 18; ++t) {
            f16x8 A0 = w2fv[(t * 2 + 0) * 64 + l];
            f16x8 A1 = w2fv[(t * 2 + 1) * 64 + l];
            f32x4 acc = f32x4{0.f, 0.f, 0.f, 0.f};
            acc = __builtin_amdgcn_mfma_f32_16x16x32_f16(A0, Bv0, acc, 0, 0, 0);
            acc = __builtin_amdgcn_mfma_f32_16x16x32_f16(A1, Bv1, acc, 0, 0, 0);
            f16x4 rv = {(_Float16)acc[0], (_Float16)acc[1],
                        (_Float16)acc[2], (_Float16)acc[3]};
            *(f16x4*)&sh_R[n][t * 16 + 4 * q] = rv;
        }
    }
    WBAR();

    // ---- v epilogue: partials -> 20-value cross-q reduce -> q==0 stores ----
    {
        float P0[8], P1[4][3];
        P_COMPUTE(P0, P1);
#pragma unroll
        for (int b = 0; b < 8; ++b) {
            P0[b] += __shfl_xor(P0[b], 16);
            P0[b] += __shfl_xor(P0[b], 32);
        }
#pragma unroll
        for (int b = 0; b < 4; ++b)
#pragma unroll
            for (int c = 0; c < 3; ++c) {
                P1[b][c] += __shfl_xor(P1[b][c], 16);
                P1[b][c] += __shfl_xor(P1[b][c], 32);
            }
        if (l < 16) {
            _Float16* rec = vsc + (size_t)pe0 * 20;   // 40B records, 8B aligned
            f16x4 o0 = {(_Float16)P0[0], (_Float16)P0[1],
                        (_Float16)P0[2], (_Float16)P0[3]};
            f16x4 o1 = {(_Float16)P0[4], (_Float16)P0[5],
                        (_Float16)P0[6], (_Float16)P0[7]};
            f16x4 o2 = {(_Float16)P1[0][0], (_Float16)P1[0][1],
                        (_Float16)P1[0][2], (_Float16)P1[1][0]};
            f16x4 o3 = {(_Float16)P1[1][1], (_Float16)P1[1][2],
                        (_Float16)P1[2][0], (_Float16)P1[2][1]};
            f16x4 o4 = {(_Float16)P1[2][2], (_Float16)P1[3][0],
                        (_Float16)P1[3][1], (_Float16)P1[3][2]};
            *(f16x4*)&rec[0]  = o0;
            *(f16x4*)&rec[4]  = o1;
            *(f16x4*)&rec[8]  = o2;
            *(f16x4*)&rec[12] = o3;
            *(f16x4*)&rec[16] = o4;
        }
    }
}

// ---------- node gather: Z precomputed; single weighted pass, zero atomics ----------
__global__ __launch_bounds__(TPB) void node_gather(
    const int* __restrict__ offs, const int* __restrict__ cntp,
    const float* __restrict__ Z,
    const float* __restrict__ evs, const _Float16* __restrict__ vsc,
    float* __restrict__ out)
{
    const int wv = threadIdx.x >> 6, lane = threadIdx.x & 63;
    const int j = blockIdx.x * 4 + wv;
    if (j >= NN) return;
    const int o0 = offs[j], cnt = cntp[j];
    const float zz = Z[j];
    const float invZ = (zz > 0.f) ? (1.f / zz) : 0.f;

    const int g = lane / 20, c = lane % 20;
    float acc = 0.f;
    if (g < 3) {
        for (int t = g; t < cnt; t += 3) {
            const float ev = evs[o0 + t];
            const float wgt = sqrtf(fmaxf(ev * invZ, 0.f));
            acc += wgt * (float)vsc[(size_t)(o0 + t) * 20 + c];
        }
    }
    const float a1 = __shfl(acc, lane + 20);
    const float a2 = __shfl(acc, lane + 40);
    if (lane < 20) out[(size_t)j * 20 + lane] = acc + a1 + a2;
}

extern "C" void kernel_launch(void* const* d_in, const int* in_sizes, int n_in,
                              void* d_out, int out_size, void* d_ws, size_t ws_size,
                              hipStream_t stream)
{
    const float* x     = (const float*)d_in[0];
    const int*   eidx  = (const int*)d_in[1];
    const float* eattr = (const float*)d_in[2];
    const float* emb   = (const float*)d_in[3];
    const float* elen  = (const float*)d_in[4];
    const float* wq0   = (const float*)d_in[5];
    const float* wq1   = (const float*)d_in[6];
    const float* wk1   = (const float*)d_in[7];
    const float* wk2   = (const float*)d_in[8];
    const float* wv1   = (const float*)d_in[9];
    const float* wv2   = (const float*)d_in[10];
    const float* wd0   = (const float*)d_in[11];
    const float* wd1   = (const float*)d_in[12];

    float* ws  = (float*)d_ws;
    float* out = (float*)d_out;

    half2v* w1pk = (half2v*)(ws + NW1K_OFF);
    half2v* w1pv = (half2v*)(ws + NW1V_OFF);
    _Float16* w2fk = (_Float16*)(ws + NW2K_OFF);
    _Float16* w2fv = (_Float16*)(ws + NW2V_OFF);
    int* cnt  = (int*)(ws + NCNT_OFF);
    int* c2   = (int*)(ws + NC2_OFF);
    float* Z  = ws + NZ_OFF;
    int* base = (int*)(ws + NBASE_OFF);
    int* offs = (int*)(ws + NOFF_OFF);
    float* evs = ws + NEVS_OFF;
    _Float16* vsc = (_Float16*)(ws + NVSC_OFF);

    // zero cnt + c2 + Z + base (contiguous) in one memset
    hipMemsetAsync(cnt, 0, (3 * NN + 8) * sizeof(int), stream);

    // prep: weights + g + histogram (1875 hist blocks)
    prep_all<<<136 + NE / TPB, TPB, 0, stream>>>(
        x, eidx, wq0, wq1, wk1, wk2, wv1, wv2, wd0, wd1,
        w1pk, w1pv, w2fk, w2fv, ws + NG_OFF, cnt);

    scan_blk<<<(NN + TPB - 1) / TPB, TPB, 0, stream>>>(cnt, offs, base);

    edge_fused<<<NE / 16, ETPB, 0, stream>>>(
        x, eidx, eattr, emb, elen,
        w1pk, (const f16x8*)w2fk, w1pv, (const f16x8*)w2fv,
        ws + NG_OFF, offs, c2, Z, evs, vsc);

    node_gather<<<(NN + 3) / 4, TPB, 0, stream>>>(offs, cnt, Z, evs, vsc, out);
}